// Round 7
// baseline (1219.851 us; speedup 1.0000x reference)
//
#include <hip/hip_runtime.h>

#define NN   100000
#define NE   3200000
#define INF_ 512
#define HIDF 64
#define OUTF 16
#define NB_SCAN ((NN + 1023) / 1024)   // 98 blocks of 1024
#define BR    128                       // bucket = 128 consecutive dst nodes
#define NBUCK ((NN + BR - 1) / BR)      // 782

// ---------------------------------------------------------------- degree ----
__global__ __launch_bounds__(256) void k_deg_count(const int* __restrict__ dst,
                                                   int* __restrict__ cnt) {
    int e = blockIdx.x * 256 + threadIdx.x;
    if (e < NE) atomicAdd(&cnt[dst[e]], 1);
}

__global__ __launch_bounds__(256) void k_dinv(const int* __restrict__ cnt,
                                              float* __restrict__ dinv) {
    int i = blockIdx.x * 256 + threadIdx.x;
    if (i < NN) dinv[i] = rsqrtf((float)(cnt[i] + 1));   // +1 self-loop
}

// ------------------------------------------------------------------ scan ----
__global__ __launch_bounds__(256) void k_scan1(const int* __restrict__ cnt,
                                               int* __restrict__ rs,
                                               int* __restrict__ bsum) {
    __shared__ int lds[256];
    int b = blockIdx.x, t = threadIdx.x;
    int base = b * 1024 + t * 4;
    int c[4];
#pragma unroll
    for (int i = 0; i < 4; ++i) { int idx = base + i; c[i] = idx < NN ? cnt[idx] : 0; }
    int tsum = c[0] + c[1] + c[2] + c[3];
    lds[t] = tsum;
    __syncthreads();
    for (int off = 1; off < 256; off <<= 1) {
        int v = lds[t];
        int a = (t >= off) ? lds[t - off] : 0;
        __syncthreads();
        lds[t] = v + a;
        __syncthreads();
    }
    int pre = (t == 0) ? 0 : lds[t - 1];
    if (t == 255) bsum[b] = lds[255];
    int run = pre;
#pragma unroll
    for (int i = 0; i < 4; ++i) { int idx = base + i; if (idx < NN) rs[idx] = run; run += c[i]; }
}

__global__ __launch_bounds__(128) void k_scan2(int* __restrict__ bsum,
                                               int* __restrict__ boff) {
    __shared__ int lds[128];
    int t = threadIdx.x;
    lds[t] = (t < NB_SCAN) ? bsum[t] : 0;
    __syncthreads();
    for (int off = 1; off < 128; off <<= 1) {
        int v = lds[t];
        int a = (t >= off) ? lds[t - off] : 0;
        __syncthreads();
        lds[t] = v + a;
        __syncthreads();
    }
    if (t < NB_SCAN) boff[t] = (t == 0) ? 0 : lds[t - 1];
}

__global__ __launch_bounds__(256) void k_scan3(int* __restrict__ rs,
                                               const int* __restrict__ boff) {
    int i = blockIdx.x * 256 + threadIdx.x;
    if (i < NN) rs[i] = rs[i] + boff[i >> 10];
    if (i == 0) rs[NN] = NE;
}

__global__ __launch_bounds__(256) void k_bcur(const int* __restrict__ rs,
                                              int* __restrict__ bcur) {
    int b = blockIdx.x * 256 + threadIdx.x;
    if (b < NBUCK) bcur[b] = rs[b * BR];
}

// -------------------------------------------------- bucketed CSR fill ------
// Pass A: scatter (src,dst) pairs into per-bucket dense regions (8B appends,
// line-friendly). Bucket region base = rs[b*BR] -- free from the node scan.
__global__ __launch_bounds__(256) void k_fillA(const int* __restrict__ src,
                                               const int* __restrict__ dst,
                                               int* __restrict__ bcur,
                                               int2* __restrict__ pairs) {
    int e = blockIdx.x * 256 + threadIdx.x;
    if (e < NE) {
        int s = src[e], d = dst[e];
        int pos = atomicAdd(&bcur[d >> 7], 1);
        pairs[pos] = make_int2(s, d);
    }
}

// Pass B: one block per bucket; per-node cursors in LDS; csr writes confined
// to the bucket's contiguous ~16KB window.
__global__ __launch_bounds__(256) void k_fillB(const int* __restrict__ rs,
                                               const int2* __restrict__ pairs,
                                               int* __restrict__ csr) {
    __shared__ int cur[BR];
    int b  = blockIdx.x;
    int t  = threadIdx.x;
    int n0 = b * BR;
    int nend = (n0 + BR < NN) ? n0 + BR : NN;
    if (t < BR && n0 + t < nend) cur[t] = rs[n0 + t];
    __syncthreads();
    int beg = rs[n0], end = rs[nend];
    for (int j = beg + t; j < end; j += 256) {
        int2 p = pairs[j];
        int pos = atomicAdd(&cur[p.y - n0], 1);
        csr[pos] = p.x;
    }
}

// ---------------------------------------------------------------- GEMM1 -----
// h1p = x @ W1, LDS-tiled. M=128, N=64, KC=32. 256 thr; 4 nodes x 8 feats ea.
#define MT 128
#define KC 32
#define XT_STR 132
#define WT_STR 68

__global__ __launch_bounds__(256) void k_gemm1(const float* __restrict__ x,
                                               const float* __restrict__ W1,
                                               float* __restrict__ h1p) {
    __shared__ float xt[KC * XT_STR];
    __shared__ float wt[KC * WT_STR];
    int t = threadIdx.x;
    int mbase = blockIdx.x * MT;

    int n0 = (t & 31) * 4;
    int f0 = (t >> 5) * 8;

    int lr = t >> 3;
    int lc = (t & 7) * 4;

    float acc[4][8];
#pragma unroll
    for (int a = 0; a < 4; ++a)
#pragma unroll
        for (int b = 0; b < 8; ++b) acc[a][b] = 0.f;

    for (int kc = 0; kc < INF_; kc += KC) {
#pragma unroll
        for (int i = 0; i < 4; ++i) {
            int row = mbase + lr + i * 32;
            int rowc = row < NN ? row : NN - 1;
            float4 v = *(const float4*)&x[(size_t)rowc * INF_ + kc + lc];
            int m = lr + i * 32;
            xt[(lc + 0) * XT_STR + m] = v.x;
            xt[(lc + 1) * XT_STR + m] = v.y;
            xt[(lc + 2) * XT_STR + m] = v.z;
            xt[(lc + 3) * XT_STR + m] = v.w;
        }
#pragma unroll
        for (int i = 0; i < 2; ++i) {
            int idx = t + 256 * i;
            int k  = idx >> 4;
            int c4 = (idx & 15) * 4;
            float4 v = *(const float4*)&W1[(size_t)(kc + k) * HIDF + c4];
            *(float4*)&wt[k * WT_STR + c4] = v;
        }
        __syncthreads();

#pragma unroll 8
        for (int k = 0; k < KC; ++k) {
            float4 xv = *(const float4*)&xt[k * XT_STR + n0];
            float4 wa = *(const float4*)&wt[k * WT_STR + f0];
            float4 wb = *(const float4*)&wt[k * WT_STR + f0 + 4];
            float xs[4] = {xv.x, xv.y, xv.z, xv.w};
            float ws[8] = {wa.x, wa.y, wa.z, wa.w, wb.x, wb.y, wb.z, wb.w};
#pragma unroll
            for (int a = 0; a < 4; ++a)
#pragma unroll
                for (int b = 0; b < 8; ++b)
                    acc[a][b] = fmaf(xs[a], ws[b], acc[a][b]);
        }
        __syncthreads();
    }

#pragma unroll
    for (int a = 0; a < 4; ++a) {
        int n = mbase + n0 + a;
        if (n < NN) {
            *(float4*)&h1p[(size_t)n * HIDF + f0]     = make_float4(acc[a][0], acc[a][1], acc[a][2], acc[a][3]);
            *(float4*)&h1p[(size_t)n * HIDF + f0 + 4] = make_float4(acc[a][4], acc[a][5], acc[a][6], acc[a][7]);
        }
    }
}

// --------------------------------------------------- layer1 aggregate ------
__global__ __launch_bounds__(256) void k_hid(const int* __restrict__ rs,
                                             const int* __restrict__ csr,
                                             const float* __restrict__ dinv,
                                             const float* __restrict__ h1p,
                                             const float* __restrict__ b1,
                                             float* __restrict__ hid) {
    int f = threadIdx.x & 63;
    int n = (blockIdx.x * 256 + threadIdx.x) >> 6;   // one wave per node
    if (n >= NN) return;
    int row = rs[n], end = rs[n + 1];
    float dn = dinv[n];
    float acc = dn * h1p[n * HIDF + f];              // self-loop

    int j = row;
    for (; j + 4 <= end; j += 4) {
        int s0 = csr[j], s1 = csr[j + 1], s2 = csr[j + 2], s3 = csr[j + 3];
        float w0 = dinv[s0], w1 = dinv[s1], w2 = dinv[s2], w3 = dinv[s3];
        acc = fmaf(h1p[s0 * HIDF + f], w0, acc);
        acc = fmaf(h1p[s1 * HIDF + f], w1, acc);
        acc = fmaf(h1p[s2 * HIDF + f], w2, acc);
        acc = fmaf(h1p[s3 * HIDF + f], w3, acc);
    }
    for (; j < end; ++j) {
        int s = csr[j];
        acc = fmaf(h1p[s * HIDF + f], dinv[s], acc);
    }
    hid[n * HIDF + f] = fmaxf(fmaf(dn, acc, b1[f]), 0.f);
}

// ---------------------------------------------------------------- GEMM2 -----
__global__ __launch_bounds__(256) void k_gemm2(const float* __restrict__ hid,
                                               const float* __restrict__ W2,
                                               float* __restrict__ h2) {
    int n = blockIdx.x * 256 + threadIdx.x;
    if (n >= NN) return;
    const float* p = hid + (size_t)n * HIDF;
    float acc[OUTF];
#pragma unroll
    for (int f = 0; f < OUTF; ++f) acc[f] = 0.f;
#pragma unroll 4
    for (int k = 0; k < HIDF; ++k) {
        float hv = p[k];
#pragma unroll
        for (int f = 0; f < OUTF; ++f)
            acc[f] = fmaf(hv, W2[k * OUTF + f], acc[f]);
    }
#pragma unroll
    for (int f = 0; f < OUTF; ++f)
        h2[(size_t)n * OUTF + f] = acc[f];
}

// --------------------------- layer2 aggregate + bias + log_softmax ---------
__global__ __launch_bounds__(256) void k_out2(const int* __restrict__ rs,
                                              const int* __restrict__ csr,
                                              const float* __restrict__ dinv,
                                              const float* __restrict__ h2,
                                              const float* __restrict__ b2,
                                              float* __restrict__ out) {
    int t = blockIdx.x * 256 + threadIdx.x;
    int n = t >> 4;
    int f = t & 15;
    if (n >= NN) return;
    int row = rs[n], end = rs[n + 1];
    float dn = dinv[n];
    float acc = dn * h2[n * OUTF + f];               // self-loop

    int j = row;
    for (; j + 2 <= end; j += 2) {
        int s0 = csr[j], s1 = csr[j + 1];
        acc = fmaf(h2[s0 * OUTF + f], dinv[s0], acc);
        acc = fmaf(h2[s1 * OUTF + f], dinv[s1], acc);
    }
    for (; j < end; ++j) {
        int s = csr[j];
        acc = fmaf(h2[s * OUTF + f], dinv[s], acc);
    }
    float v = fmaf(dn, acc, b2[f]);

    float m = v;
#pragma unroll
    for (int mask = 1; mask < 16; mask <<= 1)
        m = fmaxf(m, __shfl_xor(m, mask, 16));
    float ex = __expf(v - m);
    float s  = ex;
#pragma unroll
    for (int mask = 1; mask < 16; mask <<= 1)
        s += __shfl_xor(s, mask, 16);
    out[(size_t)n * OUTF + f] = v - (m + __logf(s));
}

// ----------------------------------------------------------------- launch --
extern "C" void kernel_launch(void* const* d_in, const int* in_sizes, int n_in,
                              void* d_out, int out_size, void* d_ws, size_t ws_size,
                              hipStream_t stream) {
    const float* x  = (const float*)d_in[0];
    const int*   ei = (const int*)d_in[1];    // [2][NE], delivered as int32
    const float* W1 = (const float*)d_in[2];
    const float* b1 = (const float*)d_in[3];
    const float* W2 = (const float*)d_in[4];
    const float* b2 = (const float*)d_in[5];
    float*       out = (float*)d_out;

    char*  ws = (char*)d_ws;
    size_t o  = 0;
    auto alloc = [&](size_t bytes) {
        void* p = ws + o;
        o = (o + bytes + 1023) & ~(size_t)1023;
        return p;
    };
    int*   cnt    = (int*)  alloc((size_t)NN * 4);
    int*   rs     = (int*)  alloc((size_t)(NN + 1) * 4);
    int*   bcur   = (int*)  alloc((size_t)NBUCK * 4);
    int*   bsum   = (int*)  alloc((size_t)NB_SCAN * 4);
    int*   boff   = (int*)  alloc((size_t)NB_SCAN * 4);
    int*   csr    = (int*)  alloc((size_t)NE * 4);
    float* dinv   = (float*)alloc((size_t)NN * 4);
    float* h1p    = (float*)alloc((size_t)NN * HIDF * 4);
    float* hid    = (float*)alloc((size_t)NN * HIDF * 4);
    float* h2     = (float*)alloc((size_t)NN * OUTF * 4);
    if (o > ws_size) return;   // insufficient scratch -> visible failure

    // pairs (25.6 MB) aliases hid: dead before k_hid writes hid.
    int2* pairs = (int2*)hid;

    const int* esrc = ei;
    const int* edst = ei + NE;

    hipMemsetAsync(cnt, 0, (size_t)NN * 4, stream);

    k_deg_count<<<(NE + 255) / 256, 256, 0, stream>>>(edst, cnt);
    k_dinv     <<<(NN + 255) / 256, 256, 0, stream>>>(cnt, dinv);
    k_scan1    <<<NB_SCAN, 256, 0, stream>>>(cnt, rs, bsum);
    k_scan2    <<<1, 128, 0, stream>>>(bsum, boff);
    k_scan3    <<<(NN + 255) / 256, 256, 0, stream>>>(rs, boff);
    k_bcur     <<<(NBUCK + 255) / 256, 256, 0, stream>>>(rs, bcur);
    k_fillA    <<<(NE + 255) / 256, 256, 0, stream>>>(esrc, edst, bcur, pairs);
    k_fillB    <<<NBUCK, 256, 0, stream>>>(rs, pairs, csr);

    k_gemm1    <<<(NN + MT - 1) / MT, 256, 0, stream>>>(x, W1, h1p);
    k_hid      <<<(NN * 64 + 255) / 256, 256, 0, stream>>>(rs, csr, dinv, h1p, b1, hid);
    k_gemm2    <<<(NN + 255) / 256, 256, 0, stream>>>(hid, W2, h2);
    k_out2     <<<(NN * OUTF + 255) / 256, 256, 0, stream>>>(rs, csr, dinv, h2, b2, out);
}

// Round 8
// 540.120 us; speedup vs baseline: 2.2585x; 2.2585x over previous
//
#include <hip/hip_runtime.h>

#define NN   100000
#define NE   3200000
#define INF_ 512
#define HIDF 64
#define OUTF 16
#define NB_SCAN ((NN + 1023) / 1024)   // 98 blocks of 1024
#define BR    128                       // bucket = 128 consecutive dst nodes
#define NBUCK ((NN + BR - 1) / BR)      // 782
#define EBLK  16384                     // edges per fillA block
#define NFB   ((NE + EBLK - 1) / EBLK)  // 196

// ---------------------------------------------------------------- degree ----
__global__ __launch_bounds__(256) void k_deg_count(const int* __restrict__ dst,
                                                   int* __restrict__ cnt) {
    int e = blockIdx.x * 256 + threadIdx.x;
    if (e < NE) atomicAdd(&cnt[dst[e]], 1);
}

__global__ __launch_bounds__(256) void k_dinv(const int* __restrict__ cnt,
                                              float* __restrict__ dinv) {
    int i = blockIdx.x * 256 + threadIdx.x;
    if (i < NN) dinv[i] = rsqrtf((float)(cnt[i] + 1));   // +1 self-loop
}

// ------------------------------------------------------------------ scan ----
__global__ __launch_bounds__(256) void k_scan1(const int* __restrict__ cnt,
                                               int* __restrict__ rs,
                                               int* __restrict__ bsum) {
    __shared__ int lds[256];
    int b = blockIdx.x, t = threadIdx.x;
    int base = b * 1024 + t * 4;
    int c[4];
#pragma unroll
    for (int i = 0; i < 4; ++i) { int idx = base + i; c[i] = idx < NN ? cnt[idx] : 0; }
    int tsum = c[0] + c[1] + c[2] + c[3];
    lds[t] = tsum;
    __syncthreads();
    for (int off = 1; off < 256; off <<= 1) {
        int v = lds[t];
        int a = (t >= off) ? lds[t - off] : 0;
        __syncthreads();
        lds[t] = v + a;
        __syncthreads();
    }
    int pre = (t == 0) ? 0 : lds[t - 1];
    if (t == 255) bsum[b] = lds[255];
    int run = pre;
#pragma unroll
    for (int i = 0; i < 4; ++i) { int idx = base + i; if (idx < NN) rs[idx] = run; run += c[i]; }
}

__global__ __launch_bounds__(128) void k_scan2(int* __restrict__ bsum,
                                               int* __restrict__ boff) {
    __shared__ int lds[128];
    int t = threadIdx.x;
    lds[t] = (t < NB_SCAN) ? bsum[t] : 0;
    __syncthreads();
    for (int off = 1; off < 128; off <<= 1) {
        int v = lds[t];
        int a = (t >= off) ? lds[t - off] : 0;
        __syncthreads();
        lds[t] = v + a;
        __syncthreads();
    }
    if (t < NB_SCAN) boff[t] = (t == 0) ? 0 : lds[t - 1];
}

__global__ __launch_bounds__(256) void k_scan3(int* __restrict__ rs,
                                               const int* __restrict__ boff) {
    int i = blockIdx.x * 256 + threadIdx.x;
    if (i < NN) rs[i] = rs[i] + boff[i >> 10];
    if (i == 0) rs[NN] = NE;
}

__global__ __launch_bounds__(256) void k_bcur(const int* __restrict__ rs,
                                              int* __restrict__ bcur) {
    int b = blockIdx.x * 256 + threadIdx.x;
    if (b < NBUCK) bcur[b] = rs[b * BR];
}

// -------------------------------------------------- bucketed CSR fill ------
// Pass A v2: block-local histogram + bulk reservation. Each block owns EBLK
// consecutive edges; 1 global atomic per (block,bucket) instead of per edge;
// pair writes are contiguous single-CU runs. Pairs packed: (src<<7)|(dst&127).
__global__ __launch_bounds__(256) void k_fillA(const int* __restrict__ src,
                                               const int* __restrict__ dst,
                                               int* __restrict__ bcur,
                                               unsigned int* __restrict__ pairs) {
    __shared__ int hist[NBUCK];   // counts, then reused as cursors
    __shared__ int rbase[NBUCK];  // reserved global base per bucket
    int t = threadIdx.x;
    int e0 = blockIdx.x * EBLK;
    int e1 = (e0 + EBLK < NE) ? e0 + EBLK : NE;

    for (int b = t; b < NBUCK; b += 256) hist[b] = 0;
    __syncthreads();

    for (int e = e0 + t; e < e1; e += 256)
        atomicAdd(&hist[dst[e] >> 7], 1);
    __syncthreads();

    for (int b = t; b < NBUCK; b += 256) {
        int c = hist[b];
        rbase[b] = c ? atomicAdd(&bcur[b], c) : 0;
        hist[b] = 0;   // reuse as running cursor
    }
    __syncthreads();

    for (int e = e0 + t; e < e1; e += 256) {
        int s = src[e], d = dst[e];
        int b = d >> 7;
        int slot = atomicAdd(&hist[b], 1);
        pairs[rbase[b] + slot] = ((unsigned)s << 7) | (unsigned)(d & 127);
    }
}

// Pass B: one block per bucket; per-node cursors in LDS; csr writes confined
// to the bucket's contiguous window.
__global__ __launch_bounds__(256) void k_fillB(const int* __restrict__ rs,
                                               const unsigned int* __restrict__ pairs,
                                               int* __restrict__ csr) {
    __shared__ int cur[BR];
    int b  = blockIdx.x;
    int t  = threadIdx.x;
    int n0 = b * BR;
    int nend = (n0 + BR < NN) ? n0 + BR : NN;
    if (t < BR && n0 + t < nend) cur[t] = rs[n0 + t];
    __syncthreads();
    int beg = rs[n0], end = rs[nend];
    for (int j = beg + t; j < end; j += 256) {
        unsigned int p = pairs[j];
        int doff = (int)(p & 127u);
        int s    = (int)(p >> 7);
        int pos = atomicAdd(&cur[doff], 1);
        csr[pos] = s;
    }
}

// ---------------------------------------------------------------- GEMM1 -----
// h1p = x @ W1, LDS-tiled. M=128, N=64, KC=32. 256 thr; 4 nodes x 8 feats ea.
#define MT 128
#define KC 32
#define XT_STR 132
#define WT_STR 68

__global__ __launch_bounds__(256) void k_gemm1(const float* __restrict__ x,
                                               const float* __restrict__ W1,
                                               float* __restrict__ h1p) {
    __shared__ float xt[KC * XT_STR];
    __shared__ float wt[KC * WT_STR];
    int t = threadIdx.x;
    int mbase = blockIdx.x * MT;

    int n0 = (t & 31) * 4;
    int f0 = (t >> 5) * 8;

    int lr = t >> 3;
    int lc = (t & 7) * 4;

    float acc[4][8];
#pragma unroll
    for (int a = 0; a < 4; ++a)
#pragma unroll
        for (int b = 0; b < 8; ++b) acc[a][b] = 0.f;

    for (int kc = 0; kc < INF_; kc += KC) {
#pragma unroll
        for (int i = 0; i < 4; ++i) {
            int row = mbase + lr + i * 32;
            int rowc = row < NN ? row : NN - 1;
            float4 v = *(const float4*)&x[(size_t)rowc * INF_ + kc + lc];
            int m = lr + i * 32;
            xt[(lc + 0) * XT_STR + m] = v.x;
            xt[(lc + 1) * XT_STR + m] = v.y;
            xt[(lc + 2) * XT_STR + m] = v.z;
            xt[(lc + 3) * XT_STR + m] = v.w;
        }
#pragma unroll
        for (int i = 0; i < 2; ++i) {
            int idx = t + 256 * i;
            int k  = idx >> 4;
            int c4 = (idx & 15) * 4;
            float4 v = *(const float4*)&W1[(size_t)(kc + k) * HIDF + c4];
            *(float4*)&wt[k * WT_STR + c4] = v;
        }
        __syncthreads();

#pragma unroll 8
        for (int k = 0; k < KC; ++k) {
            float4 xv = *(const float4*)&xt[k * XT_STR + n0];
            float4 wa = *(const float4*)&wt[k * WT_STR + f0];
            float4 wb = *(const float4*)&wt[k * WT_STR + f0 + 4];
            float xs[4] = {xv.x, xv.y, xv.z, xv.w};
            float ws[8] = {wa.x, wa.y, wa.z, wa.w, wb.x, wb.y, wb.z, wb.w};
#pragma unroll
            for (int a = 0; a < 4; ++a)
#pragma unroll
                for (int b = 0; b < 8; ++b)
                    acc[a][b] = fmaf(xs[a], ws[b], acc[a][b]);
        }
        __syncthreads();
    }

#pragma unroll
    for (int a = 0; a < 4; ++a) {
        int n = mbase + n0 + a;
        if (n < NN) {
            *(float4*)&h1p[(size_t)n * HIDF + f0]     = make_float4(acc[a][0], acc[a][1], acc[a][2], acc[a][3]);
            *(float4*)&h1p[(size_t)n * HIDF + f0 + 4] = make_float4(acc[a][4], acc[a][5], acc[a][6], acc[a][7]);
        }
    }
}

// --------------------------------------------------- layer1 aggregate ------
__global__ __launch_bounds__(256) void k_hid(const int* __restrict__ rs,
                                             const int* __restrict__ csr,
                                             const float* __restrict__ dinv,
                                             const float* __restrict__ h1p,
                                             const float* __restrict__ b1,
                                             float* __restrict__ hid) {
    int f = threadIdx.x & 63;
    int n = (blockIdx.x * 256 + threadIdx.x) >> 6;   // one wave per node
    if (n >= NN) return;
    int row = rs[n], end = rs[n + 1];
    float dn = dinv[n];
    float acc = dn * h1p[n * HIDF + f];              // self-loop

    int j = row;
    for (; j + 4 <= end; j += 4) {
        int s0 = csr[j], s1 = csr[j + 1], s2 = csr[j + 2], s3 = csr[j + 3];
        float w0 = dinv[s0], w1 = dinv[s1], w2 = dinv[s2], w3 = dinv[s3];
        acc = fmaf(h1p[s0 * HIDF + f], w0, acc);
        acc = fmaf(h1p[s1 * HIDF + f], w1, acc);
        acc = fmaf(h1p[s2 * HIDF + f], w2, acc);
        acc = fmaf(h1p[s3 * HIDF + f], w3, acc);
    }
    for (; j < end; ++j) {
        int s = csr[j];
        acc = fmaf(h1p[s * HIDF + f], dinv[s], acc);
    }
    hid[n * HIDF + f] = fmaxf(fmaf(dn, acc, b1[f]), 0.f);
}

// ---------------------------------------------------------------- GEMM2 -----
__global__ __launch_bounds__(256) void k_gemm2(const float* __restrict__ hid,
                                               const float* __restrict__ W2,
                                               float* __restrict__ h2) {
    int n = blockIdx.x * 256 + threadIdx.x;
    if (n >= NN) return;
    const float* p = hid + (size_t)n * HIDF;
    float acc[OUTF];
#pragma unroll
    for (int f = 0; f < OUTF; ++f) acc[f] = 0.f;
#pragma unroll 4
    for (int k = 0; k < HIDF; ++k) {
        float hv = p[k];
#pragma unroll
        for (int f = 0; f < OUTF; ++f)
            acc[f] = fmaf(hv, W2[k * OUTF + f], acc[f]);
    }
#pragma unroll
    for (int f = 0; f < OUTF; ++f)
        h2[(size_t)n * OUTF + f] = acc[f];
}

// --------------------------- layer2 aggregate + bias + log_softmax ---------
__global__ __launch_bounds__(256) void k_out2(const int* __restrict__ rs,
                                              const int* __restrict__ csr,
                                              const float* __restrict__ dinv,
                                              const float* __restrict__ h2,
                                              const float* __restrict__ b2,
                                              float* __restrict__ out) {
    int t = blockIdx.x * 256 + threadIdx.x;
    int n = t >> 4;
    int f = t & 15;
    if (n >= NN) return;
    int row = rs[n], end = rs[n + 1];
    float dn = dinv[n];
    float acc = dn * h2[n * OUTF + f];               // self-loop

    int j = row;
    for (; j + 2 <= end; j += 2) {
        int s0 = csr[j], s1 = csr[j + 1];
        acc = fmaf(h2[s0 * OUTF + f], dinv[s0], acc);
        acc = fmaf(h2[s1 * OUTF + f], dinv[s1], acc);
    }
    for (; j < end; ++j) {
        int s = csr[j];
        acc = fmaf(h2[s * OUTF + f], dinv[s], acc);
    }
    float v = fmaf(dn, acc, b2[f]);

    float m = v;
#pragma unroll
    for (int mask = 1; mask < 16; mask <<= 1)
        m = fmaxf(m, __shfl_xor(m, mask, 16));
    float ex = __expf(v - m);
    float s  = ex;
#pragma unroll
    for (int mask = 1; mask < 16; mask <<= 1)
        s += __shfl_xor(s, mask, 16);
    out[(size_t)n * OUTF + f] = v - (m + __logf(s));
}

// ----------------------------------------------------------------- launch --
extern "C" void kernel_launch(void* const* d_in, const int* in_sizes, int n_in,
                              void* d_out, int out_size, void* d_ws, size_t ws_size,
                              hipStream_t stream) {
    const float* x  = (const float*)d_in[0];
    const int*   ei = (const int*)d_in[1];    // [2][NE], delivered as int32
    const float* W1 = (const float*)d_in[2];
    const float* b1 = (const float*)d_in[3];
    const float* W2 = (const float*)d_in[4];
    const float* b2 = (const float*)d_in[5];
    float*       out = (float*)d_out;

    char*  ws = (char*)d_ws;
    size_t o  = 0;
    auto alloc = [&](size_t bytes) {
        void* p = ws + o;
        o = (o + bytes + 1023) & ~(size_t)1023;
        return p;
    };
    int*   cnt    = (int*)  alloc((size_t)NN * 4);
    int*   rs     = (int*)  alloc((size_t)(NN + 1) * 4);
    int*   bcur   = (int*)  alloc((size_t)NBUCK * 4);
    int*   bsum   = (int*)  alloc((size_t)NB_SCAN * 4);
    int*   boff   = (int*)  alloc((size_t)NB_SCAN * 4);
    int*   csr    = (int*)  alloc((size_t)NE * 4);
    float* dinv   = (float*)alloc((size_t)NN * 4);
    float* h1p    = (float*)alloc((size_t)NN * HIDF * 4);
    float* hid    = (float*)alloc((size_t)NN * HIDF * 4);
    float* h2     = (float*)alloc((size_t)NN * OUTF * 4);
    if (o > ws_size) return;   // insufficient scratch -> visible failure

    // pairs (12.8 MB, packed u32) aliases hid: dead before k_hid writes hid.
    unsigned int* pairs = (unsigned int*)hid;

    const int* esrc = ei;
    const int* edst = ei + NE;

    hipMemsetAsync(cnt, 0, (size_t)NN * 4, stream);

    k_deg_count<<<(NE + 255) / 256, 256, 0, stream>>>(edst, cnt);
    k_dinv     <<<(NN + 255) / 256, 256, 0, stream>>>(cnt, dinv);
    k_scan1    <<<NB_SCAN, 256, 0, stream>>>(cnt, rs, bsum);
    k_scan2    <<<1, 128, 0, stream>>>(bsum, boff);
    k_scan3    <<<(NN + 255) / 256, 256, 0, stream>>>(rs, boff);
    k_bcur     <<<(NBUCK + 255) / 256, 256, 0, stream>>>(rs, bcur);
    k_fillA    <<<NFB, 256, 0, stream>>>(esrc, edst, bcur, pairs);
    k_fillB    <<<NBUCK, 256, 0, stream>>>(rs, pairs, csr);

    k_gemm1    <<<(NN + MT - 1) / MT, 256, 0, stream>>>(x, W1, h1p);
    k_hid      <<<(NN * 64 + 255) / 256, 256, 0, stream>>>(rs, csr, dinv, h1p, b1, hid);
    k_gemm2    <<<(NN + 255) / 256, 256, 0, stream>>>(hid, W2, h2);
    k_out2     <<<(NN * OUTF + 255) / 256, 256, 0, stream>>>(rs, csr, dinv, h2, b2, out);
}

// Round 10
// 425.682 us; speedup vs baseline: 2.8656x; 1.2688x over previous
//
#include <hip/hip_runtime.h>

#define NN   100000
#define NE   3200000
#define INF_ 512
#define HIDF 64
#define OUTF 16
#define BR    128                       // bucket = 128 consecutive dst nodes
#define NBUCK ((NN + BR - 1) / BR)      // 782
#define EBLK  16384                     // edges per fillA/bhist block
#define NFB   ((NE + EBLK - 1) / EBLK)  // 196

// ------------------------------------------------------- bucket histogram --
// LDS histogram over 782 dst-buckets; 1 global atomic per (block,bucket).
__global__ __launch_bounds__(256) void k_bhist(const int* __restrict__ dst,
                                               int* __restrict__ bcnt) {
    __shared__ int hist[NBUCK];
    int t = threadIdx.x;
    int e0 = blockIdx.x * EBLK;
    int e1 = (e0 + EBLK < NE) ? e0 + EBLK : NE;
    for (int b = t; b < NBUCK; b += 256) hist[b] = 0;
    __syncthreads();
    for (int e = e0 + t; e < e1; e += 256)
        atomicAdd(&hist[dst[e] >> 7], 1);
    __syncthreads();
    for (int b = t; b < NBUCK; b += 256) {
        int c = hist[b];
        if (c) atomicAdd(&bcnt[b], c);
    }
}

// ----------------------------------------------- bucket scan (one block) ---
// Exclusive scan of bcnt[NBUCK] -> bbase[NBUCK+1]; also seeds bcur.
__global__ __launch_bounds__(256) void k_bscan(const int* __restrict__ bcnt,
                                               int* __restrict__ bbase,
                                               int* __restrict__ bcur) {
    __shared__ int lds[256];
    int t = threadIdx.x;
    int base = t * 4;
    int c[4];
#pragma unroll
    for (int i = 0; i < 4; ++i) { int idx = base + i; c[i] = idx < NBUCK ? bcnt[idx] : 0; }
    int tsum = c[0] + c[1] + c[2] + c[3];
    lds[t] = tsum;
    __syncthreads();
    for (int off = 1; off < 256; off <<= 1) {
        int v = lds[t];
        int a = (t >= off) ? lds[t - off] : 0;
        __syncthreads();
        lds[t] = v + a;
        __syncthreads();
    }
    int pre = (t == 0) ? 0 : lds[t - 1];
    int run = pre;
#pragma unroll
    for (int i = 0; i < 4; ++i) {
        int idx = base + i;
        if (idx < NBUCK) { bbase[idx] = run; bcur[idx] = run; }
        run += c[i];
    }
    if (t == 255) bbase[NBUCK] = lds[255];   // == NE
}

// -------------------------------------------------- bucketed CSR fill ------
// Pass A: block-local histogram + bulk reservation; pair writes are
// contiguous single-CU runs. Packed: (src<<7)|(dst&127).
__global__ __launch_bounds__(256) void k_fillA(const int* __restrict__ src,
                                               const int* __restrict__ dst,
                                               int* __restrict__ bcur,
                                               unsigned int* __restrict__ pairs) {
    __shared__ int hist[NBUCK];   // counts, then reused as cursors
    __shared__ int rbase[NBUCK];  // reserved global base per bucket
    int t = threadIdx.x;
    int e0 = blockIdx.x * EBLK;
    int e1 = (e0 + EBLK < NE) ? e0 + EBLK : NE;

    for (int b = t; b < NBUCK; b += 256) hist[b] = 0;
    __syncthreads();

    for (int e = e0 + t; e < e1; e += 256)
        atomicAdd(&hist[dst[e] >> 7], 1);
    __syncthreads();

    for (int b = t; b < NBUCK; b += 256) {
        int c = hist[b];
        rbase[b] = c ? atomicAdd(&bcur[b], c) : 0;
        hist[b] = 0;   // reuse as running cursor
    }
    __syncthreads();

    for (int e = e0 + t; e < e1; e += 256) {
        int s = src[e], d = dst[e];
        int b = d >> 7;
        int slot = atomicAdd(&hist[b], 1);
        pairs[rbase[b] + slot] = ((unsigned)s << 7) | (unsigned)(d & 127);
    }
}

// Pass B v2: one block per bucket. Counts per-node degrees from its pairs,
// scans them -> rs[n], dinv[n]; then reorders pairs into csr (writes confined
// to the bucket's contiguous window).
__global__ __launch_bounds__(256) void k_fillB(const int* __restrict__ bbase,
                                               const unsigned int* __restrict__ pairs,
                                               int* __restrict__ rs,
                                               float* __restrict__ dinv,
                                               int* __restrict__ csr) {
    __shared__ int cnt_s[BR];   // counts, then cursors
    __shared__ int scan_s[BR];  // inclusive-scan workspace
    int b  = blockIdx.x;
    int t  = threadIdx.x;
    int n0 = b * BR;
    int ncount = ((n0 + BR < NN) ? BR : NN - n0);
    int gbase = bbase[b], gend = bbase[b + 1];

    if (t < BR) cnt_s[t] = 0;
    __syncthreads();

    // count per-node in-degrees within this bucket
    for (int j = gbase + t; j < gend; j += 256)
        atomicAdd(&cnt_s[pairs[j] & 127u], 1);
    __syncthreads();

    int myc = (t < BR) ? cnt_s[t] : 0;
    if (t < BR) scan_s[t] = myc;
    __syncthreads();
#pragma unroll
    for (int off = 1; off < BR; off <<= 1) {
        int a = 0;
        if (t < BR && t >= off) a = scan_s[t - off];
        __syncthreads();
        if (t < BR) scan_s[t] += a;
        __syncthreads();
    }
    // exclusive prefix = inclusive - own
    if (t < BR) {
        int start = gbase + scan_s[t] - myc;
        if (t < ncount) {
            rs[n0 + t]   = start;
            dinv[n0 + t] = rsqrtf((float)(myc + 1));   // +1 self-loop
        }
        cnt_s[t] = start;   // cursor
    }
    if (b == NBUCK - 1 && t == 0) rs[NN] = gend;   // == NE
    __syncthreads();

    // reorder into csr
    for (int j = gbase + t; j < gend; j += 256) {
        unsigned int p = pairs[j];
        int pos = atomicAdd(&cnt_s[p & 127u], 1);
        csr[pos] = (int)(p >> 7);
    }
}

// ---------------------------------------------------------------- GEMM1 -----
// h1p = x @ W1, LDS-tiled. M=128, N=64, KC=32. 256 thr; 4 nodes x 8 feats ea.
#define MT 128
#define KC 32
#define XT_STR 132
#define WT_STR 68

__global__ __launch_bounds__(256) void k_gemm1(const float* __restrict__ x,
                                               const float* __restrict__ W1,
                                               float* __restrict__ h1p) {
    __shared__ float xt[KC * XT_STR];
    __shared__ float wt[KC * WT_STR];
    int t = threadIdx.x;
    int mbase = blockIdx.x * MT;

    int n0 = (t & 31) * 4;
    int f0 = (t >> 5) * 8;

    int lr = t >> 3;
    int lc = (t & 7) * 4;

    float acc[4][8];
#pragma unroll
    for (int a = 0; a < 4; ++a)
#pragma unroll
        for (int b = 0; b < 8; ++b) acc[a][b] = 0.f;

    for (int kc = 0; kc < INF_; kc += KC) {
#pragma unroll
        for (int i = 0; i < 4; ++i) {
            int row = mbase + lr + i * 32;
            int rowc = row < NN ? row : NN - 1;
            float4 v = *(const float4*)&x[(size_t)rowc * INF_ + kc + lc];
            int m = lr + i * 32;
            xt[(lc + 0) * XT_STR + m] = v.x;
            xt[(lc + 1) * XT_STR + m] = v.y;
            xt[(lc + 2) * XT_STR + m] = v.z;
            xt[(lc + 3) * XT_STR + m] = v.w;
        }
#pragma unroll
        for (int i = 0; i < 2; ++i) {
            int idx = t + 256 * i;
            int k  = idx >> 4;
            int c4 = (idx & 15) * 4;
            float4 v = *(const float4*)&W1[(size_t)(kc + k) * HIDF + c4];
            *(float4*)&wt[k * WT_STR + c4] = v;
        }
        __syncthreads();

#pragma unroll 8
        for (int k = 0; k < KC; ++k) {
            float4 xv = *(const float4*)&xt[k * XT_STR + n0];
            float4 wa = *(const float4*)&wt[k * WT_STR + f0];
            float4 wb = *(const float4*)&wt[k * WT_STR + f0 + 4];
            float xs[4] = {xv.x, xv.y, xv.z, xv.w};
            float ws[8] = {wa.x, wa.y, wa.z, wa.w, wb.x, wb.y, wb.z, wb.w};
#pragma unroll
            for (int a = 0; a < 4; ++a)
#pragma unroll
                for (int b = 0; b < 8; ++b)
                    acc[a][b] = fmaf(xs[a], ws[b], acc[a][b]);
        }
        __syncthreads();
    }

#pragma unroll
    for (int a = 0; a < 4; ++a) {
        int n = mbase + n0 + a;
        if (n < NN) {
            *(float4*)&h1p[(size_t)n * HIDF + f0]     = make_float4(acc[a][0], acc[a][1], acc[a][2], acc[a][3]);
            *(float4*)&h1p[(size_t)n * HIDF + f0 + 4] = make_float4(acc[a][4], acc[a][5], acc[a][6], acc[a][7]);
        }
    }
}

// --------------------------------------------------- layer1 aggregate ------
__global__ __launch_bounds__(256) void k_hid(const int* __restrict__ rs,
                                             const int* __restrict__ csr,
                                             const float* __restrict__ dinv,
                                             const float* __restrict__ h1p,
                                             const float* __restrict__ b1,
                                             float* __restrict__ hid) {
    int f = threadIdx.x & 63;
    int n = (blockIdx.x * 256 + threadIdx.x) >> 6;   // one wave per node
    if (n >= NN) return;
    int row = rs[n], end = rs[n + 1];
    float dn = dinv[n];
    float acc = dn * h1p[n * HIDF + f];              // self-loop

    int j = row;
    for (; j + 4 <= end; j += 4) {
        int s0 = csr[j], s1 = csr[j + 1], s2 = csr[j + 2], s3 = csr[j + 3];
        float w0 = dinv[s0], w1 = dinv[s1], w2 = dinv[s2], w3 = dinv[s3];
        acc = fmaf(h1p[s0 * HIDF + f], w0, acc);
        acc = fmaf(h1p[s1 * HIDF + f], w1, acc);
        acc = fmaf(h1p[s2 * HIDF + f], w2, acc);
        acc = fmaf(h1p[s3 * HIDF + f], w3, acc);
    }
    for (; j < end; ++j) {
        int s = csr[j];
        acc = fmaf(h1p[s * HIDF + f], dinv[s], acc);
    }
    hid[n * HIDF + f] = fmaxf(fmaf(dn, acc, b1[f]), 0.f);
}

// ---------------------------------------------------------------- GEMM2 -----
__global__ __launch_bounds__(256) void k_gemm2(const float* __restrict__ hid,
                                               const float* __restrict__ W2,
                                               float* __restrict__ h2) {
    int n = blockIdx.x * 256 + threadIdx.x;
    if (n >= NN) return;
    const float* p = hid + (size_t)n * HIDF;
    float acc[OUTF];
#pragma unroll
    for (int f = 0; f < OUTF; ++f) acc[f] = 0.f;
#pragma unroll 4
    for (int k = 0; k < HIDF; ++k) {
        float hv = p[k];
#pragma unroll
        for (int f = 0; f < OUTF; ++f)
            acc[f] = fmaf(hv, W2[k * OUTF + f], acc[f]);
    }
#pragma unroll
    for (int f = 0; f < OUTF; ++f)
        h2[(size_t)n * OUTF + f] = acc[f];
}

// --------------------------- layer2 aggregate + bias + log_softmax ---------
__global__ __launch_bounds__(256) void k_out2(const int* __restrict__ rs,
                                              const int* __restrict__ csr,
                                              const float* __restrict__ dinv,
                                              const float* __restrict__ h2,
                                              const float* __restrict__ b2,
                                              float* __restrict__ out) {
    int t = blockIdx.x * 256 + threadIdx.x;
    int n = t >> 4;
    int f = t & 15;
    if (n >= NN) return;
    int row = rs[n], end = rs[n + 1];
    float dn = dinv[n];
    float acc = dn * h2[n * OUTF + f];               // self-loop

    int j = row;
    for (; j + 2 <= end; j += 2) {
        int s0 = csr[j], s1 = csr[j + 1];
        acc = fmaf(h2[s0 * OUTF + f], dinv[s0], acc);
        acc = fmaf(h2[s1 * OUTF + f], dinv[s1], acc);
    }
    for (; j < end; ++j) {
        int s = csr[j];
        acc = fmaf(h2[s * OUTF + f], dinv[s], acc);
    }
    float v = fmaf(dn, acc, b2[f]);

    float m = v;
#pragma unroll
    for (int mask = 1; mask < 16; mask <<= 1)
        m = fmaxf(m, __shfl_xor(m, mask, 16));
    float ex = __expf(v - m);
    float s  = ex;
#pragma unroll
    for (int mask = 1; mask < 16; mask <<= 1)
        s += __shfl_xor(s, mask, 16);
    out[(size_t)n * OUTF + f] = v - (m + __logf(s));
}

// ----------------------------------------------------------------- launch --
extern "C" void kernel_launch(void* const* d_in, const int* in_sizes, int n_in,
                              void* d_out, int out_size, void* d_ws, size_t ws_size,
                              hipStream_t stream) {
    const float* x  = (const float*)d_in[0];
    const int*   ei = (const int*)d_in[1];    // [2][NE], delivered as int32
    const float* W1 = (const float*)d_in[2];
    const float* b1 = (const float*)d_in[3];
    const float* W2 = (const float*)d_in[4];
    const float* b2 = (const float*)d_in[5];
    float*       out = (float*)d_out;

    char*  ws = (char*)d_ws;
    size_t o  = 0;
    auto alloc = [&](size_t bytes) {
        void* p = ws + o;
        o = (o + bytes + 1023) & ~(size_t)1023;
        return p;
    };
    int*   bcnt   = (int*)  alloc((size_t)NBUCK * 4);
    int*   bbase  = (int*)  alloc((size_t)(NBUCK + 1) * 4);
    int*   bcur   = (int*)  alloc((size_t)NBUCK * 4);
    int*   rs     = (int*)  alloc((size_t)(NN + 1) * 4);
    int*   csr    = (int*)  alloc((size_t)NE * 4);
    float* dinv   = (float*)alloc((size_t)NN * 4);
    float* h1p    = (float*)alloc((size_t)NN * HIDF * 4);
    float* hid    = (float*)alloc((size_t)NN * HIDF * 4);
    float* h2     = (float*)alloc((size_t)NN * OUTF * 4);
    if (o > ws_size) return;   // insufficient scratch -> visible failure

    // pairs (12.8 MB, packed u32) aliases hid: dead before k_hid writes hid.
    unsigned int* pairs = (unsigned int*)hid;

    const int* esrc = ei;
    const int* edst = ei + NE;

    hipMemsetAsync(bcnt, 0, (size_t)NBUCK * 4, stream);

    k_bhist <<<NFB, 256, 0, stream>>>(edst, bcnt);
    k_bscan <<<1, 256, 0, stream>>>(bcnt, bbase, bcur);
    k_fillA <<<NFB, 256, 0, stream>>>(esrc, edst, bcur, pairs);
    k_fillB <<<NBUCK, 256, 0, stream>>>(bbase, pairs, rs, dinv, csr);

    k_gemm1 <<<(NN + MT - 1) / MT, 256, 0, stream>>>(x, W1, h1p);
    k_hid   <<<(NN * 64 + 255) / 256, 256, 0, stream>>>(rs, csr, dinv, h1p, b1, hid);
    k_gemm2 <<<(NN + 255) / 256, 256, 0, stream>>>(hid, W2, h2);
    k_out2  <<<(NN * OUTF + 255) / 256, 256, 0, stream>>>(rs, csr, dinv, h2, b2, out);
}

// Round 11
// 345.718 us; speedup vs baseline: 3.5285x; 1.2313x over previous
//
#include <hip/hip_runtime.h>

#define NN   100000
#define NE   3200000
#define INF_ 512
#define HIDF 64
#define OUTF 16
#define BR    128                       // bucket = 128 consecutive dst nodes
#define NBUCK ((NN + BR - 1) / BR)      // 782
#define EBLK  16384                     // edges per fillA/bhist block
#define NFB   ((NE + EBLK - 1) / EBLK)  // 196

typedef __bf16 bf16x8 __attribute__((ext_vector_type(8)));
typedef float  f32x4  __attribute__((ext_vector_type(4)));

__device__ inline unsigned short f2bfu(float f) {      // RNE fp32 -> bf16 bits
    unsigned u = __builtin_bit_cast(unsigned, f);
    u += 0x7FFFu + ((u >> 16) & 1u);
    return (unsigned short)(u >> 16);
}
__device__ inline __bf16 bfbits(unsigned short h) {
    return __builtin_bit_cast(__bf16, h);
}
__device__ inline float bf2f(unsigned short h) {
    unsigned u = (unsigned)h << 16;
    return __builtin_bit_cast(float, u);
}

// ------------------------------------------------------- bucket histogram --
__global__ __launch_bounds__(256) void k_bhist(const int* __restrict__ dst,
                                               int* __restrict__ bcnt) {
    __shared__ int hist[NBUCK];
    int t = threadIdx.x;
    int e0 = blockIdx.x * EBLK;
    int e1 = (e0 + EBLK < NE) ? e0 + EBLK : NE;
    for (int b = t; b < NBUCK; b += 256) hist[b] = 0;
    __syncthreads();
    for (int e = e0 + t; e < e1; e += 256)
        atomicAdd(&hist[dst[e] >> 7], 1);
    __syncthreads();
    for (int b = t; b < NBUCK; b += 256) {
        int c = hist[b];
        if (c) atomicAdd(&bcnt[b], c);
    }
}

// ----------------------------------------------- bucket scan (one block) ---
__global__ __launch_bounds__(256) void k_bscan(const int* __restrict__ bcnt,
                                               int* __restrict__ bbase,
                                               int* __restrict__ bcur) {
    __shared__ int lds[256];
    int t = threadIdx.x;
    int base = t * 4;
    int c[4];
#pragma unroll
    for (int i = 0; i < 4; ++i) { int idx = base + i; c[i] = idx < NBUCK ? bcnt[idx] : 0; }
    int tsum = c[0] + c[1] + c[2] + c[3];
    lds[t] = tsum;
    __syncthreads();
    for (int off = 1; off < 256; off <<= 1) {
        int v = lds[t];
        int a = (t >= off) ? lds[t - off] : 0;
        __syncthreads();
        lds[t] = v + a;
        __syncthreads();
    }
    int pre = (t == 0) ? 0 : lds[t - 1];
    int run = pre;
#pragma unroll
    for (int i = 0; i < 4; ++i) {
        int idx = base + i;
        if (idx < NBUCK) { bbase[idx] = run; bcur[idx] = run; }
        run += c[i];
    }
    if (t == 255) bbase[NBUCK] = lds[255];   // == NE
}

// -------------------------------------------------- bucketed CSR fill ------
__global__ __launch_bounds__(256) void k_fillA(const int* __restrict__ src,
                                               const int* __restrict__ dst,
                                               int* __restrict__ bcur,
                                               unsigned int* __restrict__ pairs) {
    __shared__ int hist[NBUCK];
    __shared__ int rbase[NBUCK];
    int t = threadIdx.x;
    int e0 = blockIdx.x * EBLK;
    int e1 = (e0 + EBLK < NE) ? e0 + EBLK : NE;

    for (int b = t; b < NBUCK; b += 256) hist[b] = 0;
    __syncthreads();
    for (int e = e0 + t; e < e1; e += 256)
        atomicAdd(&hist[dst[e] >> 7], 1);
    __syncthreads();
    for (int b = t; b < NBUCK; b += 256) {
        int c = hist[b];
        rbase[b] = c ? atomicAdd(&bcur[b], c) : 0;
        hist[b] = 0;
    }
    __syncthreads();
    for (int e = e0 + t; e < e1; e += 256) {
        int s = src[e], d = dst[e];
        int b = d >> 7;
        int slot = atomicAdd(&hist[b], 1);
        pairs[rbase[b] + slot] = ((unsigned)s << 7) | (unsigned)(d & 127);
    }
}

__global__ __launch_bounds__(256) void k_fillB(const int* __restrict__ bbase,
                                               const unsigned int* __restrict__ pairs,
                                               int* __restrict__ rs,
                                               float* __restrict__ dinv,
                                               int* __restrict__ csr) {
    __shared__ int cnt_s[BR];
    __shared__ int scan_s[BR];
    int b  = blockIdx.x;
    int t  = threadIdx.x;
    int n0 = b * BR;
    int ncount = ((n0 + BR < NN) ? BR : NN - n0);
    int gbase = bbase[b], gend = bbase[b + 1];

    if (t < BR) cnt_s[t] = 0;
    __syncthreads();
    for (int j = gbase + t; j < gend; j += 256)
        atomicAdd(&cnt_s[pairs[j] & 127u], 1);
    __syncthreads();

    int myc = (t < BR) ? cnt_s[t] : 0;
    if (t < BR) scan_s[t] = myc;
    __syncthreads();
#pragma unroll
    for (int off = 1; off < BR; off <<= 1) {
        int a = 0;
        if (t < BR && t >= off) a = scan_s[t - off];
        __syncthreads();
        if (t < BR) scan_s[t] += a;
        __syncthreads();
    }
    if (t < BR) {
        int start = gbase + scan_s[t] - myc;
        if (t < ncount) {
            rs[n0 + t]   = start;
            dinv[n0 + t] = rsqrtf((float)(myc + 1));
        }
        cnt_s[t] = start;
    }
    if (b == NBUCK - 1 && t == 0) rs[NN] = gend;
    __syncthreads();

    for (int j = gbase + t; j < gend; j += 256) {
        unsigned int p = pairs[j];
        int pos = atomicAdd(&cnt_s[p & 127u], 1);
        csr[pos] = (int)(p >> 7);
    }
}

// ---------------------------------------------------------------- GEMM1 -----
// h1b (bf16) = x @ W1 via MFMA 16x16x32 bf16.
// Block: 256 thr = 4 waves; 64 nodes/block (wave w -> rows w*16..+16).
// W1 staged once to LDS bf16 (padded stride 66); no barrier in K-loop;
// each lane loads its own A-fragment straight from global x (fp32->bf16).
#define GM 64

__global__ __launch_bounds__(256) void k_gemm1(const float* __restrict__ x,
                                               const float* __restrict__ W1,
                                               unsigned short* __restrict__ h1b) {
    __shared__ unsigned short w1b[INF_ * 66];   // 66 KB
    int t = threadIdx.x;

    // ---- stage W1 [512][64] fp32 -> w1b bf16 (row-coalesced)
#pragma unroll
    for (int i = 0; i < 32; ++i) {
        int fidx = t + i * 256;          // 0..8191 float4-slots
        int k  = fidx >> 4;
        int n4 = (fidx & 15) * 4;
        float4 v = *(const float4*)&W1[(size_t)k * HIDF + n4];
        ushort4 u;
        u.x = f2bfu(v.x); u.y = f2bfu(v.y); u.z = f2bfu(v.z); u.w = f2bfu(v.w);
        *(ushort4*)&w1b[k * 66 + n4] = u;
    }
    __syncthreads();

    int lane = t & 63;
    int w    = t >> 6;
    int m    = lane & 15;    // A row / D col / B col
    int kg   = lane >> 4;    // k-group 0..3
    int mb   = blockIdx.x * GM;

    int rowi = mb + w * 16 + m;
    size_t xrow = (size_t)((rowi < NN) ? rowi : NN - 1);
    const float* xp = x + xrow * INF_ + kg * 4;

    f32x4 acc0 = {0.f,0.f,0.f,0.f}, acc1 = acc0, acc2 = acc0, acc3 = acc0;

#pragma unroll 2
    for (int ks = 0; ks < 16; ++ks) {
        float4 xa = *(const float4*)(xp + ks * 32);
        float4 xb = *(const float4*)(xp + ks * 32 + 16);
        bf16x8 A;
        A[0] = bfbits(f2bfu(xa.x)); A[1] = bfbits(f2bfu(xa.y));
        A[2] = bfbits(f2bfu(xa.z)); A[3] = bfbits(f2bfu(xa.w));
        A[4] = bfbits(f2bfu(xb.x)); A[5] = bfbits(f2bfu(xb.y));
        A[6] = bfbits(f2bfu(xb.z)); A[7] = bfbits(f2bfu(xb.w));

        const unsigned short* wr = &w1b[(ks * 32 + kg * 4) * 66 + m];
#pragma unroll
        for (int n0t = 0; n0t < 4; ++n0t) {
            const unsigned short* wn = wr + n0t * 16;
            bf16x8 B;
            B[0] = bfbits(wn[0]);        B[1] = bfbits(wn[66]);
            B[2] = bfbits(wn[132]);      B[3] = bfbits(wn[198]);
            B[4] = bfbits(wn[16 * 66]);  B[5] = bfbits(wn[17 * 66]);
            B[6] = bfbits(wn[18 * 66]);  B[7] = bfbits(wn[19 * 66]);
            f32x4 c = (n0t == 0) ? acc0 : (n0t == 1) ? acc1 : (n0t == 2) ? acc2 : acc3;
            c = __builtin_amdgcn_mfma_f32_16x16x32_bf16(A, B, c, 0, 0, 0);
            if      (n0t == 0) acc0 = c;
            else if (n0t == 1) acc1 = c;
            else if (n0t == 2) acc2 = c;
            else               acc3 = c;
        }
    }

    // ---- store D: row = kg*4 + r, col = n0t*16 + m
#pragma unroll
    for (int r = 0; r < 4; ++r) {
        int node = mb + w * 16 + kg * 4 + r;
        if (node < NN) {
            size_t o = (size_t)node * HIDF + m;
            h1b[o +  0] = f2bfu(acc0[r]);
            h1b[o + 16] = f2bfu(acc1[r]);
            h1b[o + 32] = f2bfu(acc2[r]);
            h1b[o + 48] = f2bfu(acc3[r]);
        }
    }
}

// --------------------------------------------------- layer1 aggregate ------
// One wave per dst node, lane = feature (64). Gathers bf16 h1p rows (128B).
__global__ __launch_bounds__(256) void k_hid(const int* __restrict__ rs,
                                             const int* __restrict__ csr,
                                             const float* __restrict__ dinv,
                                             const unsigned short* __restrict__ h1b,
                                             const float* __restrict__ b1,
                                             float* __restrict__ hid) {
    int f = threadIdx.x & 63;
    int n = (blockIdx.x * 256 + threadIdx.x) >> 6;
    if (n >= NN) return;
    int row = rs[n], end = rs[n + 1];
    float dn = dinv[n];
    float acc = dn * bf2f(h1b[(size_t)n * HIDF + f]);   // self-loop

    int j = row;
    for (; j + 4 <= end; j += 4) {
        int s0 = csr[j], s1 = csr[j + 1], s2 = csr[j + 2], s3 = csr[j + 3];
        float w0 = dinv[s0], w1 = dinv[s1], w2 = dinv[s2], w3 = dinv[s3];
        acc = fmaf(bf2f(h1b[(size_t)s0 * HIDF + f]), w0, acc);
        acc = fmaf(bf2f(h1b[(size_t)s1 * HIDF + f]), w1, acc);
        acc = fmaf(bf2f(h1b[(size_t)s2 * HIDF + f]), w2, acc);
        acc = fmaf(bf2f(h1b[(size_t)s3 * HIDF + f]), w3, acc);
    }
    for (; j < end; ++j) {
        int s = csr[j];
        acc = fmaf(bf2f(h1b[(size_t)s * HIDF + f]), dinv[s], acc);
    }
    hid[(size_t)n * HIDF + f] = fmaxf(fmaf(dn, acc, b1[f]), 0.f);
}

// ---------------------------------------------------------------- GEMM2 -----
__global__ __launch_bounds__(256) void k_gemm2(const float* __restrict__ hid,
                                               const float* __restrict__ W2,
                                               float* __restrict__ h2) {
    int n = blockIdx.x * 256 + threadIdx.x;
    if (n >= NN) return;
    const float* p = hid + (size_t)n * HIDF;
    float acc[OUTF];
#pragma unroll
    for (int f = 0; f < OUTF; ++f) acc[f] = 0.f;
#pragma unroll 4
    for (int k = 0; k < HIDF; ++k) {
        float hv = p[k];
#pragma unroll
        for (int f = 0; f < OUTF; ++f)
            acc[f] = fmaf(hv, W2[k * OUTF + f], acc[f]);
    }
#pragma unroll
    for (int f = 0; f < OUTF; ++f)
        h2[(size_t)n * OUTF + f] = acc[f];
}

// --------------------------- layer2 aggregate + bias + log_softmax ---------
__global__ __launch_bounds__(256) void k_out2(const int* __restrict__ rs,
                                              const int* __restrict__ csr,
                                              const float* __restrict__ dinv,
                                              const float* __restrict__ h2,
                                              const float* __restrict__ b2,
                                              float* __restrict__ out) {
    int t = blockIdx.x * 256 + threadIdx.x;
    int n = t >> 4;
    int f = t & 15;
    if (n >= NN) return;
    int row = rs[n], end = rs[n + 1];
    float dn = dinv[n];
    float acc = dn * h2[(size_t)n * OUTF + f];

    int j = row;
    for (; j + 2 <= end; j += 2) {
        int s0 = csr[j], s1 = csr[j + 1];
        acc = fmaf(h2[(size_t)s0 * OUTF + f], dinv[s0], acc);
        acc = fmaf(h2[(size_t)s1 * OUTF + f], dinv[s1], acc);
    }
    for (; j < end; ++j) {
        int s = csr[j];
        acc = fmaf(h2[(size_t)s * OUTF + f], dinv[s], acc);
    }
    float v = fmaf(dn, acc, b2[f]);

    float m = v;
#pragma unroll
    for (int mask = 1; mask < 16; mask <<= 1)
        m = fmaxf(m, __shfl_xor(m, mask, 16));
    float ex = __expf(v - m);
    float s  = ex;
#pragma unroll
    for (int mask = 1; mask < 16; mask <<= 1)
        s += __shfl_xor(s, mask, 16);
    out[(size_t)n * OUTF + f] = v - (m + __logf(s));
}

// ----------------------------------------------------------------- launch --
extern "C" void kernel_launch(void* const* d_in, const int* in_sizes, int n_in,
                              void* d_out, int out_size, void* d_ws, size_t ws_size,
                              hipStream_t stream) {
    const float* x  = (const float*)d_in[0];
    const int*   ei = (const int*)d_in[1];    // [2][NE], delivered as int32
    const float* W1 = (const float*)d_in[2];
    const float* b1 = (const float*)d_in[3];
    const float* W2 = (const float*)d_in[4];
    const float* b2 = (const float*)d_in[5];
    float*       out = (float*)d_out;

    char*  ws = (char*)d_ws;
    size_t o  = 0;
    auto alloc = [&](size_t bytes) {
        void* p = ws + o;
        o = (o + bytes + 1023) & ~(size_t)1023;
        return p;
    };
    int*            bcnt  = (int*)           alloc((size_t)NBUCK * 4);
    int*            bbase = (int*)           alloc((size_t)(NBUCK + 1) * 4);
    int*            bcur  = (int*)           alloc((size_t)NBUCK * 4);
    int*            rs    = (int*)           alloc((size_t)(NN + 1) * 4);
    int*            csr   = (int*)           alloc((size_t)NE * 4);
    float*          dinv  = (float*)         alloc((size_t)NN * 4);
    unsigned short* h1b   = (unsigned short*)alloc((size_t)NN * HIDF * 2);
    float*          hid   = (float*)         alloc((size_t)NN * HIDF * 4);
    float*          h2    = (float*)         alloc((size_t)NN * OUTF * 4);
    if (o > ws_size) return;   // insufficient scratch -> visible failure

    // pairs (12.8 MB, packed u32) aliases hid (25.6 MB): dead before k_hid.
    unsigned int* pairs = (unsigned int*)hid;

    const int* esrc = ei;
    const int* edst = ei + NE;

    hipMemsetAsync(bcnt, 0, (size_t)NBUCK * 4, stream);

    k_bhist <<<NFB, 256, 0, stream>>>(edst, bcnt);
    k_bscan <<<1, 256, 0, stream>>>(bcnt, bbase, bcur);
    k_fillA <<<NFB, 256, 0, stream>>>(esrc, edst, bcur, pairs);
    k_fillB <<<NBUCK, 256, 0, stream>>>(bbase, pairs, rs, dinv, csr);

    k_gemm1 <<<(NN + GM - 1) / GM, 256, 0, stream>>>(x, W1, h1b);
    k_hid   <<<(NN * 64 + 255) / 256, 256, 0, stream>>>(rs, csr, dinv, h1b, b1, hid);
    k_gemm2 <<<(NN + 255) / 256, 256, 0, stream>>>(hid, W2, h2);
    k_out2  <<<(NN * OUTF + 255) / 256, 256, 0, stream>>>(rs, csr, dinv, h2, b2, out);
}